// Round 4
// baseline (872.535 us; speedup 1.0000x reference)
//
#include <hip/hip_runtime.h>
#include <math.h>

// Problem constants
#define BB    2
#define NN    1024
#define CC    768
#define HH    12
#define HPP   24
#define HD    64
#define SCALE 0.125f

typedef float fvec4 __attribute__((ext_vector_type(4)));

// workspace layout (floats)
#define SEG   (2*1024*768)   // 1,572,864 floats per tensor
#define QOFF  0              // q_tok: (B*N, 768) token-major
#define KOFF  (SEG)          // k_t:   (B, 768, N) transposed
#define VOFF  (2*SEG)        // v:     (B, H, N, HD)
#define HOFF  (3*SEG)        // head_out: (B, N, C)

// LDS strides for the 128x64 GEMM tiles
#define ASTR 132             // 128 + 4 pad ; 132*4 = 528 B = 33*16 -> rows 16B aligned
#define BSTR 68              // 64 + 4 pad  ; 272 B = 17*16

// ---------------------------------------------------------------------------
// Kernel 1: fused QKV projection.  x(2048,768) @ [Wqk;Wv]^T.
// 128x64 tile, 8x4 per thread, double-buffered LDS, vectorized ds_read_b128
// fragment loads (3 LDS instr / kk instead of 12 scalar).
// ---------------------------------------------------------------------------
__global__ __launch_bounds__(256)
void qkv_gemm(const float* __restrict__ x, const float* __restrict__ Wqk,
              const float* __restrict__ Wv, float* __restrict__ ws)
{
    __shared__ __align__(16) float As[2][16*ASTR];   // 16.9 KB
    __shared__ __align__(16) float Bs[2][16*BSTR];   //  8.7 KB
    float* qtok = ws + QOFF;
    float* kt   = ws + KOFF;
    float* vws  = ws + VOFF;

    const int tid = threadIdx.x;
    const int bn  = blockIdx.x;            // 0..35 (2304/64)
    const int bm  = blockIdx.y;            // 0..15 (2048/128)
    const int tx  = tid & 15, ty = tid >> 4;

    const int am  = tid >> 1, ak = (tid & 1) * 8;     // A stage: 2 float4 / thread
    const int bnr = tid >> 2, bk = (tid & 3) * 4;     // B stage: 1 float4 / thread

    const float* Ap = x + (size_t)(bm*128 + am) * 768 + ak;
    const int jrow  = bn*64 + bnr;
    const float* Bp = (jrow < 1536) ? (Wqk + (size_t)jrow * 768 + bk)
                                    : (Wv  + (size_t)(jrow - 1536) * 768 + bk);

    float acc[8][4] = {};

    float4 a0 = *(const float4*)(Ap);
    float4 a1 = *(const float4*)(Ap + 4);
    float4 bv = *(const float4*)(Bp);
#pragma unroll
    for (int j = 0; j < 4; ++j) {
        As[0][(ak+j)*ASTR + am]   = ((const float*)&a0)[j];
        As[0][(ak+4+j)*ASTR + am] = ((const float*)&a1)[j];
        Bs[0][(bk+j)*BSTR + bnr]  = ((const float*)&bv)[j];
    }
    __syncthreads();

    for (int t = 0; t < 48; ++t) {
        const int cur = t & 1;
        if (t < 47) {
            a0 = *(const float4*)(Ap + (t+1)*16);
            a1 = *(const float4*)(Ap + (t+1)*16 + 4);
            bv = *(const float4*)(Bp + (t+1)*16);
        }
        const float* Asb = As[cur];
        const float* Bsb = Bs[cur];
#pragma unroll
        for (int kk = 0; kk < 16; ++kk) {
            const float4 av0 = *(const float4*)(Asb + kk*ASTR + ty*8);
            const float4 av1 = *(const float4*)(Asb + kk*ASTR + ty*8 + 4);
            const float4 bvv = *(const float4*)(Bsb + kk*BSTR + tx*4);
            const float a[8] = {av0.x,av0.y,av0.z,av0.w,av1.x,av1.y,av1.z,av1.w};
            const float b[4] = {bvv.x,bvv.y,bvv.z,bvv.w};
#pragma unroll
            for (int i = 0; i < 8; ++i)
#pragma unroll
                for (int j = 0; j < 4; ++j)
                    acc[i][j] = fmaf(a[i], b[j], acc[i][j]);
        }
        if (t < 47) {
#pragma unroll
            for (int j = 0; j < 4; ++j) {
                As[cur^1][(ak+j)*ASTR + am]   = ((const float*)&a0)[j];
                As[cur^1][(ak+4+j)*ASTR + am] = ((const float*)&a1)[j];
                Bs[cur^1][(bk+j)*BSTR + bnr]  = ((const float*)&bv)[j];
            }
        }
        __syncthreads();
    }

    // epilogue scatter (block-uniform region)
    const int colbase = bn*64 + tx*4;
    if (colbase < 768) {
#pragma unroll
        for (int i = 0; i < 8; ++i) {
            const int trow = bm*128 + ty*8 + i;
            float4 o = {acc[i][0], acc[i][1], acc[i][2], acc[i][3]};
            *(float4*)(qtok + (size_t)trow*768 + colbase) = o;
        }
    } else if (colbase < 1536) {
        const int p = colbase - 768;                  // h*64+d
#pragma unroll
        for (int i = 0; i < 8; ++i) {
            const int trow = bm*128 + ty*8 + i;
            const int b = trow >> 10, n = trow & 1023;
#pragma unroll
            for (int j = 0; j < 4; ++j)
                kt[((size_t)(b*768 + p + j))*NN + n] = acc[i][j];
        }
    } else {
        const int p = colbase - 1536;                 // h = p>>6, d = p&63 (4-aligned)
#pragma unroll
        for (int i = 0; i < 8; ++i) {
            const int trow = bm*128 + ty*8 + i;
            const int b = trow >> 10, n = trow & 1023;
            float4 o = {acc[i][0], acc[i][1], acc[i][2], acc[i][3]};
            *(float4*)(vws + (((size_t)b*HH + (p >> 6))*NN + n)*HD + (p & 63)) = o;
        }
    }
}

// ---------------------------------------------------------------------------
// Kernel 2: per block = 2 consecutive tokens; one K float4 load feeds both
// tokens' logits.  XCD pinning keeps one batch's K per XCD L2.
// ---------------------------------------------------------------------------
__global__ __launch_bounds__(256, 2)
void attn_expand(const float* __restrict__ qtok, const float* __restrict__ kt,
                 const float* __restrict__ Wexp, float* __restrict__ aexp)
{
    __shared__ __align__(16) float qs[2*CC];
    __shared__ float wexp_s[HPP * HH];
    __shared__ float smax[2][HH * 4];
    __shared__ float ssum[2][HH * 4];

    const int tid  = threadIdx.x;
    const int lane = tid & 63, wid = tid >> 6;
    const int x    = blockIdx.x & 7;
    const int b    = x >> 2;
    const int np   = ((x & 3) << 7) | (blockIdx.x >> 3);
    const int n0   = np << 1;
    const int m4   = tid;

    const fvec4* qsrc = (const fvec4*)(qtok + (size_t)(b*NN + n0) * CC);
    ((fvec4*)qs)[tid] = qsrc[tid];
    if (tid < 128) ((fvec4*)qs)[256 + tid] = qsrc[256 + tid];
    for (int i2 = tid; i2 < HPP*HH; i2 += 256) wexp_s[i2] = Wexp[i2];
    __syncthreads();

    fvec4 l0[HH], l1[HH];
#pragma unroll
    for (int h = 0; h < HH; ++h) {
        fvec4 a0 = {0.f,0.f,0.f,0.f}, a1 = {0.f,0.f,0.f,0.f};
        const fvec4* kr = ((const fvec4*)kt) + (size_t)(b*768 + h*64) * 256 + m4;
        const float* q0p = qs + h*64;
        const float* q1p = qs + CC + h*64;
#pragma unroll 8
        for (int d = 0; d < 64; ++d) {
            const fvec4 kv = kr[(size_t)d * 256];
            const float qa = q0p[d];
            const float qb = q1p[d];
            a0.x = fmaf(kv.x, qa, a0.x); a0.y = fmaf(kv.y, qa, a0.y);
            a0.z = fmaf(kv.z, qa, a0.z); a0.w = fmaf(kv.w, qa, a0.w);
            a1.x = fmaf(kv.x, qb, a1.x); a1.y = fmaf(kv.y, qb, a1.y);
            a1.z = fmaf(kv.z, qb, a1.z); a1.w = fmaf(kv.w, qb, a1.w);
        }
        l0[h].x = a0.x*SCALE; l0[h].y = a0.y*SCALE;
        l0[h].z = a0.z*SCALE; l0[h].w = a0.w*SCALE;
        l1[h].x = a1.x*SCALE; l1[h].y = a1.y*SCALE;
        l1[h].z = a1.z*SCALE; l1[h].w = a1.w*SCALE;
    }

#pragma unroll
    for (int h = 0; h < HH; ++h) {
        float t0 = fmaxf(fmaxf(l0[h].x, l0[h].y), fmaxf(l0[h].z, l0[h].w));
        float t1 = fmaxf(fmaxf(l1[h].x, l1[h].y), fmaxf(l1[h].z, l1[h].w));
#pragma unroll
        for (int off = 32; off > 0; off >>= 1) {
            t0 = fmaxf(t0, __shfl_xor(t0, off, 64));
            t1 = fmaxf(t1, __shfl_xor(t1, off, 64));
        }
        if (lane == 0) { smax[0][h*4 + wid] = t0; smax[1][h*4 + wid] = t1; }
    }
    __syncthreads();

#pragma unroll
    for (int h = 0; h < HH; ++h) {
        const float m0 = fmaxf(fmaxf(smax[0][h*4+0], smax[0][h*4+1]),
                               fmaxf(smax[0][h*4+2], smax[0][h*4+3]));
        const float m1 = fmaxf(fmaxf(smax[1][h*4+0], smax[1][h*4+1]),
                               fmaxf(smax[1][h*4+2], smax[1][h*4+3]));
        l0[h].x = __expf(l0[h].x - m0); l0[h].y = __expf(l0[h].y - m0);
        l0[h].z = __expf(l0[h].z - m0); l0[h].w = __expf(l0[h].w - m0);
        l1[h].x = __expf(l1[h].x - m1); l1[h].y = __expf(l1[h].y - m1);
        l1[h].z = __expf(l1[h].z - m1); l1[h].w = __expf(l1[h].w - m1);
        float s0 = (l0[h].x + l0[h].y) + (l0[h].z + l0[h].w);
        float s1 = (l1[h].x + l1[h].y) + (l1[h].z + l1[h].w);
#pragma unroll
        for (int off = 32; off > 0; off >>= 1) {
            s0 += __shfl_xor(s0, off, 64);
            s1 += __shfl_xor(s1, off, 64);
        }
        if (lane == 0) { ssum[0][h*4 + wid] = s0; ssum[1][h*4 + wid] = s1; }
    }
    __syncthreads();

#pragma unroll
    for (int h = 0; h < HH; ++h) {
        const float i0 = 1.f / (ssum[0][h*4+0] + ssum[0][h*4+1] +
                                ssum[0][h*4+2] + ssum[0][h*4+3]);
        const float i1 = 1.f / (ssum[1][h*4+0] + ssum[1][h*4+1] +
                                ssum[1][h*4+2] + ssum[1][h*4+3]);
        l0[h].x *= i0; l0[h].y *= i0; l0[h].z *= i0; l0[h].w *= i0;
        l1[h].x *= i1; l1[h].y *= i1; l1[h].z *= i1; l1[h].w *= i1;
    }

    fvec4* ab = ((fvec4*)aexp) + ((size_t)b*HPP*NN + n0) * 256;
#pragma unroll 4
    for (int o = 0; o < HPP; ++o) {
        fvec4 e0 = {0.f,0.f,0.f,0.f}, e1 = {0.f,0.f,0.f,0.f};
#pragma unroll
        for (int h = 0; h < HH; ++h) {
            const float w = wexp_s[o*HH + h];
            e0.x = fmaf(w, l0[h].x, e0.x); e0.y = fmaf(w, l0[h].y, e0.y);
            e0.z = fmaf(w, l0[h].z, e0.z); e0.w = fmaf(w, l0[h].w, e0.w);
            e1.x = fmaf(w, l1[h].x, e1.x); e1.y = fmaf(w, l1[h].y, e1.y);
            e1.z = fmaf(w, l1[h].z, e1.z); e1.w = fmaf(w, l1[h].w, e1.w);
        }
        fvec4* p0 = ab + (size_t)o * NN * 256 + m4;
        __builtin_nontemporal_store(e0, p0);
        __builtin_nontemporal_store(e1, p0 + 256);
    }
}

// ---------------------------------------------------------------------------
// Kernel 3 (v4): 1024 threads, 4 tokens per block (256 threads / token).
// Conv register-resident (shfl taps, ping-pong channel prefetch, no barriers
// in channel loop).  PV in 3 groups of 4 heads: 16 waves = (head, d-half,
// m-half) units, each V float4 load feeds ALL 4 tokens (V L2 traffic 1.5 GB),
// m-half partials combined via LDS.
// ---------------------------------------------------------------------------
__global__ __launch_bounds__(1024, 4)
void conv_red_pv(const float* __restrict__ aexp, const float* __restrict__ Wloc,
                 const float* __restrict__ bloc, const float* __restrict__ Wred,
                 const float* __restrict__ vws, float* __restrict__ hout)
{
    __shared__ __align__(16) float probs[4][4][NN];       // 64 KB: 4 tokens x 4 heads
    __shared__ __align__(16) float4 part[4][4][2][2][8];  // 8 KB partials
    __shared__ float redbuf[4][HH][4];

    const int tid  = threadIdx.x;
    const int lane = tid & 63;
    const int w    = tid >> 6;          // wave 0..15
    const int tk   = tid >> 8;          // token in group 0..3
    const int wq   = (tid >> 6) & 3;    // wave within token-quarter
    const int t8   = tid & 255;         // m float4 index 0..255

    const int x  = blockIdx.x & 7;      // XCD slot
    const int b  = x >> 2;
    const int np = ((x & 3) << 6) | (blockIdx.x >> 3);   // 0..255
    const int n0 = np << 2;
    const int n  = n0 + tk;

    const bool rv0 = n > 0, rv2 = n < NN - 1;

    float4 acc[HH];
#pragma unroll
    for (int i = 0; i < HH; ++i) acc[i] = make_float4(0.f,0.f,0.f,0.f);

    auto loadch = [&](int o, float4 ld[3], float hl[3], float hr[3]) {
        const float* cb = aexp + ((size_t)(b*HPP + o) * NN + (size_t)(n-1)) * NN;
#pragma unroll
        for (int r = 0; r < 3; ++r) {
            const bool ok = (r == 0) ? rv0 : (r == 2 ? rv2 : true);
            const float* rp = cb + (size_t)r * NN;
            if (ok) {
                ld[r] = ((const float4*)rp)[t8];
                hl[r] = (lane == 0  && wq > 0) ? rp[4*t8 - 1] : 0.f;
                hr[r] = (lane == 63 && wq < 3) ? rp[4*t8 + 4] : 0.f;
            } else {
                ld[r] = make_float4(0.f,0.f,0.f,0.f);
                hl[r] = 0.f; hr[r] = 0.f;
            }
        }
    };

    auto convstep = [&](int o, const float4 ld[3], const float hl[3], const float hr[3]) {
        const float* wl = Wloc + o*9;
        const float  bb = bloc[o];
        float v0 = bb, v1 = bb, v2 = bb, v3 = bb;
#pragma unroll
        for (int r = 0; r < 3; ++r) {
            const float w0 = wl[r*3+0], w1 = wl[r*3+1], w2 = wl[r*3+2];
            const float4 c = ld[r];
            float lf = __shfl_up(c.w, 1, 64);
            float rt = __shfl_down(c.x, 1, 64);
            if (lane == 0)  lf = hl[r];
            if (lane == 63) rt = hr[r];
            v0 = fmaf(w0, lf,  v0); v0 = fmaf(w1, c.x, v0); v0 = fmaf(w2, c.y, v0);
            v1 = fmaf(w0, c.x, v1); v1 = fmaf(w1, c.y, v1); v1 = fmaf(w2, c.z, v1);
            v2 = fmaf(w0, c.y, v2); v2 = fmaf(w1, c.z, v2); v2 = fmaf(w2, c.w, v2);
            v3 = fmaf(w0, c.z, v3); v3 = fmaf(w1, c.w, v3); v3 = fmaf(w2, rt,  v3);
        }
        v0 = fmaxf(v0, 0.f); v1 = fmaxf(v1, 0.f);
        v2 = fmaxf(v2, 0.f); v3 = fmaxf(v3, 0.f);
#pragma unroll
        for (int i = 0; i < HH; ++i) {
            const float wr = Wred[i*HPP + o];
            acc[i].x = fmaf(wr, v0, acc[i].x);
            acc[i].y = fmaf(wr, v1, acc[i].y);
            acc[i].z = fmaf(wr, v2, acc[i].z);
            acc[i].w = fmaf(wr, v3, acc[i].w);
        }
    };

    // ping-pong channel pipeline, no register rotation
    float4 ldA[3], ldB[3]; float hlA[3], hrA[3], hlB[3], hrB[3];
    loadch(0, ldA, hlA, hrA);
    loadch(1, ldB, hlB, hrB);
    for (int o = 0; o < HPP; o += 2) {
        convstep(o, ldA, hlA, hrA);
        if (o + 2 < HPP) loadch(o + 2, ldA, hlA, hrA);
        convstep(o + 1, ldB, hlB, hrB);
        if (o + 3 < HPP) loadch(o + 3, ldB, hlB, hrB);
    }
#pragma unroll
    for (int i = 0; i < HH; ++i) {
        acc[i].x *= SCALE; acc[i].y *= SCALE;
        acc[i].z *= SCALE; acc[i].w *= SCALE;
    }

    // --- softmax over m per (token, head) --------------------------------
#pragma unroll
    for (int i = 0; i < HH; ++i) {
        float tm = fmaxf(fmaxf(acc[i].x, acc[i].y), fmaxf(acc[i].z, acc[i].w));
#pragma unroll
        for (int off = 32; off > 0; off >>= 1) tm = fmaxf(tm, __shfl_xor(tm, off, 64));
        if (lane == 0) redbuf[tk][i][wq] = tm;
    }
    __syncthreads();
    float mh_[HH];
#pragma unroll
    for (int i = 0; i < HH; ++i)
        mh_[i] = fmaxf(fmaxf(redbuf[tk][i][0], redbuf[tk][i][1]),
                       fmaxf(redbuf[tk][i][2], redbuf[tk][i][3]));
    __syncthreads();

#pragma unroll
    for (int i = 0; i < HH; ++i) {
        acc[i].x = __expf(acc[i].x - mh_[i]);
        acc[i].y = __expf(acc[i].y - mh_[i]);
        acc[i].z = __expf(acc[i].z - mh_[i]);
        acc[i].w = __expf(acc[i].w - mh_[i]);
        float s = (acc[i].x + acc[i].y) + (acc[i].z + acc[i].w);
#pragma unroll
        for (int off = 32; off > 0; off >>= 1) s += __shfl_xor(s, off, 64);
        if (lane == 0) redbuf[tk][i][wq] = s;
    }
    __syncthreads();
#pragma unroll
    for (int i = 0; i < HH; ++i) {
        const float inv = 1.f / (redbuf[tk][i][0] + redbuf[tk][i][1] +
                                 redbuf[tk][i][2] + redbuf[tk][i][3]);
        acc[i].x *= inv; acc[i].y *= inv; acc[i].z *= inv; acc[i].w *= inv;
    }

    // --- PV: 3 groups of 4 heads; 16 waves = (head, d-half, m-half) -------
    const int hq = w & 3;          // head within group
    const int dh = (w >> 2) & 1;   // d half
    const int mhf = w >> 3;        // m half
    const int mg = lane >> 3;      // m sub-group 0..7
    const int dq = lane & 7;       // float4 within d-half

    for (int g = 0; g < 3; ++g) {
        __syncthreads();   // part reads of prev group done before PV writes part
#pragma unroll
        for (int q2 = 0; q2 < 4; ++q2)
            ((float4*)&probs[tk][q2][0])[t8] = acc[g*4 + q2];
        __syncthreads();

        const int h = g*4 + hq;
        const float4* vp = ((const float4*)vws)
                         + ((size_t)(b*HH + h) * NN) * 16 + dh*8 + dq;
        const float* pr0 = &probs[0][hq][0];
        const float* pr1 = &probs[1][hq][0];
        const float* pr2 = &probs[2][hq][0];
        const float* pr3 = &probs[3][hq][0];
        const int mbase = mhf*512 + mg;
        float4 a0 = make_float4(0.f,0.f,0.f,0.f);
        float4 a1 = make_float4(0.f,0.f,0.f,0.f);
        float4 a2 = make_float4(0.f,0.f,0.f,0.f);
        float4 a3 = make_float4(0.f,0.f,0.f,0.f);
#pragma unroll 8
        for (int it = 0; it < 64; ++it) {
            const int m = mbase + it*8;
            const float4 vv = vp[(size_t)m * 16];
            const float p0 = pr0[m], p1 = pr1[m], p2 = pr2[m], p3 = pr3[m];
            a0.x = fmaf(p0, vv.x, a0.x); a0.y = fmaf(p0, vv.y, a0.y);
            a0.z = fmaf(p0, vv.z, a0.z); a0.w = fmaf(p0, vv.w, a0.w);
            a1.x = fmaf(p1, vv.x, a1.x); a1.y = fmaf(p1, vv.y, a1.y);
            a1.z = fmaf(p1, vv.z, a1.z); a1.w = fmaf(p1, vv.w, a1.w);
            a2.x = fmaf(p2, vv.x, a2.x); a2.y = fmaf(p2, vv.y, a2.y);
            a2.z = fmaf(p2, vv.z, a2.z); a2.w = fmaf(p2, vv.w, a2.w);
            a3.x = fmaf(p3, vv.x, a3.x); a3.y = fmaf(p3, vv.y, a3.y);
            a3.z = fmaf(p3, vv.z, a3.z); a3.w = fmaf(p3, vv.w, a3.w);
        }
#pragma unroll
        for (int off = 8; off < 64; off <<= 1) {
            a0.x += __shfl_xor(a0.x, off, 64); a0.y += __shfl_xor(a0.y, off, 64);
            a0.z += __shfl_xor(a0.z, off, 64); a0.w += __shfl_xor(a0.w, off, 64);
            a1.x += __shfl_xor(a1.x, off, 64); a1.y += __shfl_xor(a1.y, off, 64);
            a1.z += __shfl_xor(a1.z, off, 64); a1.w += __shfl_xor(a1.w, off, 64);
            a2.x += __shfl_xor(a2.x, off, 64); a2.y += __shfl_xor(a2.y, off, 64);
            a2.z += __shfl_xor(a2.z, off, 64); a2.w += __shfl_xor(a2.w, off, 64);
            a3.x += __shfl_xor(a3.x, off, 64); a3.y += __shfl_xor(a3.y, off, 64);
            a3.z += __shfl_xor(a3.z, off, 64); a3.w += __shfl_xor(a3.w, off, 64);
        }
        if (mg == 0) {
            part[0][hq][dh][mhf][dq] = a0;
            part[1][hq][dh][mhf][dq] = a1;
            part[2][hq][dh][mhf][dq] = a2;
            part[3][hq][dh][mhf][dq] = a3;
        }
        __syncthreads();
        if (lane < 16) {
            const int tok = w >> 2, hq2 = w & 3;
            const int dh2 = lane >> 3, dq2 = lane & 7;
            const float4 s0 = part[tok][hq2][dh2][0][dq2];
            const float4 s1 = part[tok][hq2][dh2][1][dq2];
            float4 sum = {s0.x+s1.x, s0.y+s1.y, s0.z+s1.z, s0.w+s1.w};
            *(float4*)(hout + ((size_t)(b*NN + n0 + tok))*CC
                       + (g*4+hq2)*HD + dh2*32 + dq2*4) = sum;
        }
    }
}

// ---------------------------------------------------------------------------
// Kernel 4: final projection  out = head_out @ Wproj^T + bias
// Same 128x64 double-buffered structure with vectorized LDS reads.
// ---------------------------------------------------------------------------
__global__ __launch_bounds__(256)
void proj_gemm(const float* __restrict__ A, const float* __restrict__ Wp,
               const float* __restrict__ bias, float* __restrict__ out)
{
    __shared__ __align__(16) float As[2][16*ASTR];
    __shared__ __align__(16) float Bs[2][16*BSTR];

    const int tid = threadIdx.x;
    const int bn  = blockIdx.x;            // 0..11
    const int bm  = blockIdx.y;            // 0..15
    const int tx  = tid & 15, ty = tid >> 4;

    const int am  = tid >> 1, ak = (tid & 1) * 8;
    const int bnr = tid >> 2, bk = (tid & 3) * 4;

    const float* Ap = A  + (size_t)(bm*128 + am) * 768 + ak;
    const float* Bp = Wp + (size_t)(bn*64 + bnr) * 768 + bk;

    float acc[8][4] = {};

    float4 a0 = *(const float4*)(Ap);
    float4 a1 = *(const float4*)(Ap + 4);
    float4 bv = *(const float4*)(Bp);
#pragma unroll
    for (int j = 0; j < 4; ++j) {
        As[0][(ak+j)*ASTR + am]   = ((const float*)&a0)[j];
        As[0][(ak+4+j)*ASTR + am] = ((const float*)&a1)[j];
        Bs[0][(bk+j)*BSTR + bnr]  = ((const float*)&bv)[j];
    }
    __syncthreads();

    for (int t = 0; t < 48; ++t) {
        const int cur = t & 1;
        if (t < 47) {
            a0 = *(const float4*)(Ap + (t+1)*16);
            a1 = *(const float4*)(Ap + (t+1)*16 + 4);
            bv = *(const float4*)(Bp + (t+1)*16);
        }
        const float* Asb = As[cur];
        const float* Bsb = Bs[cur];
#pragma unroll
        for (int kk = 0; kk < 16; ++kk) {
            const float4 av0 = *(const float4*)(Asb + kk*ASTR + ty*8);
            const float4 av1 = *(const float4*)(Asb + kk*ASTR + ty*8 + 4);
            const float4 bvv = *(const float4*)(Bsb + kk*BSTR + tx*4);
            const float a[8] = {av0.x,av0.y,av0.z,av0.w,av1.x,av1.y,av1.z,av1.w};
            const float b[4] = {bvv.x,bvv.y,bvv.z,bvv.w};
#pragma unroll
            for (int i = 0; i < 8; ++i)
#pragma unroll
                for (int j = 0; j < 4; ++j)
                    acc[i][j] = fmaf(a[i], b[j], acc[i][j]);
        }
        if (t < 47) {
#pragma unroll
            for (int j = 0; j < 4; ++j) {
                As[cur^1][(ak+j)*ASTR + am]   = ((const float*)&a0)[j];
                As[cur^1][(ak+4+j)*ASTR + am] = ((const float*)&a1)[j];
                Bs[cur^1][(bk+j)*BSTR + bnr]  = ((const float*)&bv)[j];
            }
        }
        __syncthreads();
    }

    const int colbase = bn*64 + tx*4;
    const float4 bb = *(const float4*)(bias + colbase);
#pragma unroll
    for (int i = 0; i < 8; ++i) {
        const int trow = bm*128 + ty*8 + i;
        float4 o = {acc[i][0] + bb.x, acc[i][1] + bb.y,
                    acc[i][2] + bb.z, acc[i][3] + bb.w};
        *(float4*)(out + (size_t)trow*768 + colbase) = o;
    }
}

// ---------------------------------------------------------------------------
extern "C" void kernel_launch(void* const* d_in, const int* in_sizes, int n_in,
                              void* d_out, int out_size, void* d_ws, size_t ws_size,
                              hipStream_t stream)
{
    const float* x     = (const float*)d_in[0];
    const float* Wqk   = (const float*)d_in[1];
    const float* Wv    = (const float*)d_in[2];
    const float* Wexp  = (const float*)d_in[3];
    const float* Wloc  = (const float*)d_in[4];
    const float* bloc  = (const float*)d_in[5];
    const float* Wred  = (const float*)d_in[6];
    const float* Wproj = (const float*)d_in[7];
    const float* bproj = (const float*)d_in[8];

    float* out  = (float*)d_out;              // (B,N,C)
    float* aexp = out + (size_t)SEG;          // (B,HP,N,N)
    float* ws   = (float*)d_ws;

    qkv_gemm   <<<dim3(36, 16), 256, 0, stream>>>(x, Wqk, Wv, ws);
    attn_expand<<<dim3(BB * NN / 2), 256, 0, stream>>>(ws + QOFF, ws + KOFF, Wexp, aexp);
    conv_red_pv<<<dim3(BB * NN / 4), 1024, 0, stream>>>(aexp, Wloc, bloc, Wred,
                                                        ws + VOFF, ws + HOFF);
    proj_gemm  <<<dim3(12, 16), 256, 0, stream>>>(ws + HOFF, Wproj, bproj, out);
}